// Round 1
// 645.046 us; speedup vs baseline: 1.5379x; 1.5379x over previous
//
#include <hip/hip_runtime.h>
#include <math.h>
#include <stdint.h>

#define BATCH 8
#define NTOK  4096
#define DIM   256
#define SK    256
#define BQ    64      // q rows per block
#define BM    128     // m cols per m-tile iteration
#define CAND  40      // max candidates kept per query (4 slices x top-10)

typedef __attribute__((ext_vector_type(8))) _Float16 half8;  // 8 fp16 (4 VGPRs)
typedef __attribute__((ext_vector_type(4))) float float4v;   // 4 f32 acc

#define GLOAD_LDS16(gp, lp)                                                    \
  __builtin_amdgcn_global_load_lds(                                            \
      (const __attribute__((address_space(1))) unsigned int*)(gp),             \
      (__attribute__((address_space(3))) unsigned int*)(lp), 16, 0, 0)

// ---------------- threefry2x32 (JAX partitionable counter mode) ----------------
__device__ __forceinline__ uint32_t rotl32(uint32_t v, uint32_t r) {
  return (v << r) | (v >> (32u - r));
}
__device__ __forceinline__ void tf_round4(uint32_t& x0, uint32_t& x1,
                                          uint32_t r0, uint32_t r1,
                                          uint32_t r2, uint32_t r3) {
  x0 += x1; x1 = rotl32(x1, r0); x1 ^= x0;
  x0 += x1; x1 = rotl32(x1, r1); x1 ^= x0;
  x0 += x1; x1 = rotl32(x1, r2); x1 ^= x0;
  x0 += x1; x1 = rotl32(x1, r3); x1 ^= x0;
}
__device__ __forceinline__ uint32_t threefry_bits32(uint32_t c_hi, uint32_t c_lo) {
  const uint32_t k0 = 0u, k1 = 42u;
  const uint32_t k2 = k0 ^ k1 ^ 0x1BD11BDAu;
  uint32_t x0 = c_hi + k0;
  uint32_t x1 = c_lo + k1;
  tf_round4(x0, x1, 13u, 15u, 26u, 6u);  x0 += k1; x1 += k2 + 1u;
  tf_round4(x0, x1, 17u, 29u, 16u, 24u); x0 += k2; x1 += k0 + 2u;
  tf_round4(x0, x1, 13u, 15u, 26u, 6u);  x0 += k0; x1 += k1 + 3u;
  tf_round4(x0, x1, 17u, 29u, 16u, 24u); x0 += k1; x1 += k2 + 4u;
  tf_round4(x0, x1, 13u, 15u, 26u, 6u);  x0 += k2; x1 += k0 + 5u;
  return x0 ^ x1;
}

// ---------------- kernel 1: fp16 cast + row squared norms ----------------
__global__ __launch_bounds__(256) void tofp16_rowsq_kernel(
    const float* __restrict__ x, unsigned short* __restrict__ xh,
    float* __restrict__ sqf) {
  const int row  = blockIdx.x * 4 + (threadIdx.x >> 6);   // [0, BATCH*NTOK)
  const int lane = threadIdx.x & 63;
  const float* xr = x + (size_t)row * DIM;
  double acc = 0.0;
#pragma unroll
  for (int i = 0; i < 4; ++i) {
    const float v = xr[lane + i * 64];
    const _Float16 h = (_Float16)v;                       // RNE cast, no overflow for N(0,1)
    xh[(size_t)row * DIM + lane + i * 64] = *(const unsigned short*)&h;
    acc += (double)v * (double)v;
  }
#pragma unroll
  for (int off = 32; off > 0; off >>= 1) acc += __shfl_down(acc, off, 64);
  if (lane == 0) sqf[row] = (float)acc;
}

// ---------------- kernel 2: MFMA single-pass fp16 GEMM + candidate top-10 ------
// LDS swizzle scheme (rule #21: linear global_load_lds dest, inverse-swizzled
// per-lane GLOBAL source, swizzled ds_read):
//   A panel [64][256] shorts (512B rows, 32 x 16B slots): slot ^= (row & 7)
//   B slice [128][32]  shorts ( 64B rows,  4 x 16B slots): slot ^= ((row>>1) & 3)
//   C (transposed [col][row] f32):      row_idx ^= ((col & 7) << 2)
// All three verified uniform across the 32 banks (<=2 lanes/bank).
__global__ __launch_bounds__(256, 2) void gemm_knn_kernel(
    const unsigned short* __restrict__ xh, const float* __restrict__ sqf,
    int* __restrict__ cand) {
  __shared__ union {
    unsigned short A[BQ][DIM];                       // 32 KB (prologue only)
    struct {
      unsigned short B[2][BM][32];                   // 16 KB double-buffered slice
      float C[BQ][64];                               // 16 KB dot half-tile (transposed)
    } s;
    struct { float mv[256][10]; unsigned short mi[256][10]; } M;  // 15.3 KB
  } U;

  const int b  = blockIdx.x >> 6;                    // 64 q-tiles per batch
  const int qt = blockIdx.x & 63;
  const int q0 = qt * BQ;
  const int t  = threadIdx.x;
  const int w  = t >> 6;
  const int l  = t & 63;
  const int lr = l & 15;

  const unsigned short* xhb = xh + (size_t)b * NTOK * DIM;
  const float* sqb = sqf + b * NTOK;

  // ---- stage A panel (swizzled content, linear LDS dest) ----
#pragma unroll
  for (int is = 0; is < 8; ++is) {
    const int row  = is * 8 + (t >> 5);
    const int slot = (t & 31) ^ (row & 7);
    GLOAD_LDS16(xhb + (size_t)(q0 + row) * DIM + slot * 8,
                (char*)&U.A[0][0] + is * 4096 + t * 16);
  }
  __syncthreads();

  // ---- hoist the ENTIRE A panel into registers: af[kk][i], 128 VGPRs ----
  half8 af[8][4];
#pragma unroll
  for (int kk = 0; kk < 8; ++kk)
#pragma unroll
    for (int i = 0; i < 4; ++i) {
      const int arow  = i * 16 + lr;
      const int abyte = (kk * 64 + ((l >> 4) << 4)) ^ ((lr & 7) << 4);
      af[kk][i] = *(const half8*)((const char*)&U.A[arow][0] + abyte);
    }
  __syncthreads();   // all waves done with A region before B dbuf overlays it

  const int qg_t = q0 + (t & 63);                    // this thread's scan query
  const float sqq = sqb[qg_t];

  float tv[10]; int ti[10];
#pragma unroll
  for (int j = 0; j < 10; ++j) { tv[j] = 3.0e38f; ti[j] = 0; }

  auto stageB = [&](int buf, int m0s, int kb) {
#pragma unroll
    for (int is = 0; is < 2; ++is) {
      const int row  = is * 64 + (t >> 2);
      const int slot = (t & 3) ^ ((row >> 1) & 3);
      GLOAD_LDS16(xhb + (size_t)(m0s + row) * DIM + kb + slot * 8,
                  (char*)&U.s.B[buf][0][0] + is * 4096 + t * 16);
    }
  };

  // prologue: first slice into buf 0
  stageB(0, 0, 0);
  __syncthreads();

  float* Cf = &U.s.C[0][0];

  for (int mt = 0; mt < NTOK / BM; ++mt) {
    const int m0 = mt * BM;
    float4v acc[4][2];
#pragma unroll
    for (int i = 0; i < 4; ++i)
#pragma unroll
      for (int j = 0; j < 2; ++j) acc[i][j] = (float4v){0.f, 0.f, 0.f, 0.f};

#pragma unroll
    for (int kk = 0; kk < 8; ++kk) {
      // issue next-slice prefetch FIRST (overlaps ds_read + MFMA below;
      // the end-of-iteration barrier's vmcnt(0) drain is exactly when it's needed)
      if (!(mt == NTOK / BM - 1 && kk == 7)) {
        const int nkb = (kk == 7) ? 0 : (kk + 1) * 32;
        const int nm0 = (kk == 7) ? m0 + BM : m0;
        stageB((kk + 1) & 1, nm0, nkb);
      }
      half8 bf[2];
#pragma unroll
      for (int j = 0; j < 2; ++j) {
        const int brow  = w * 32 + j * 16 + lr;
        const int bbyte = ((l >> 4) ^ ((lr >> 1) & 3)) << 4;
        bf[j] = *(const half8*)((const char*)&U.s.B[kk & 1][brow][0] + bbyte);
      }
#pragma unroll
      for (int i = 0; i < 4; ++i)
#pragma unroll
        for (int j = 0; j < 2; ++j)
          acc[i][j] = __builtin_amdgcn_mfma_f32_16x16x32_f16(af[kk][i], bf[j], acc[i][j], 0, 0, 0);
      __syncthreads();   // one barrier per K-step: drains prefetch, guards dbuf
    }

    // epilogue: two 64x64 halves through transposed+swizzled C
#pragma unroll
    for (int h = 0; h < 2; ++h) {
      __syncthreads();
      if ((w >> 1) == h) {
#pragma unroll
        for (int i = 0; i < 4; ++i)
#pragma unroll
          for (int j = 0; j < 2; ++j) {
            const int col  = (w & 1) * 32 + j * 16 + lr;          // within half
            const int rowb = (i * 16 + (l >> 4) * 4) ^ ((lr & 7) << 2);
            *(float4v*)&Cf[col * 64 + rowb] = acc[i][j];          // ds_write_b128
          }
      }
      __syncthreads();
      {
        const int q = t & 63;
        const int s = t >> 6;
#pragma unroll
        for (int i2 = 0; i2 < 16; ++i2) {
          const int ml = s * 16 + i2;                  // within half
          const int mg = m0 + h * 64 + ml;             // global token index
          if (mg == (q0 + q)) continue;                // exclude self
          const float dot = Cf[ml * 64 + (q ^ ((ml & 7) << 2))];
          const float d2a = sqq + sqb[mg] - 2.0f * dot;
          if (d2a < tv[9]) {
            tv[9] = d2a; ti[9] = mg;
#pragma unroll
            for (int k2 = 9; k2 > 0; --k2)
              if (tv[k2] < tv[k2 - 1]) {
                float tf2 = tv[k2]; tv[k2] = tv[k2 - 1]; tv[k2 - 1] = tf2;
                int tix = ti[k2]; ti[k2] = ti[k2 - 1]; ti[k2 - 1] = tix;
              }
          }
        }
      }
    }
  }

  // merge: dump per-thread top-10, then 64 threads build candidate lists
  __syncthreads();
#pragma unroll
  for (int j = 0; j < 10; ++j) { U.M.mv[t][j] = tv[j]; U.M.mi[t][j] = (unsigned short)ti[j]; }
  __syncthreads();
  if (t < 64) {
    const int q = t;
    float t5[5] = {3.0e38f, 3.0e38f, 3.0e38f, 3.0e38f, 3.0e38f};
    for (int s = 0; s < 4; ++s)
      for (int j = 0; j < 10; ++j) {
        const float v = U.M.mv[q + s * 64][j];
        if (v < t5[4]) {
          t5[4] = v;
#pragma unroll
          for (int k2 = 4; k2 > 0; --k2)
            if (t5[k2] < t5[k2 - 1]) { float tf2 = t5[k2]; t5[k2] = t5[k2 - 1]; t5[k2 - 1] = tf2; }
        }
      }
    // fp16 single-pass margin: worst-case |d2a - d2| <= 4*2^-11*||x||*||y|| ~ 0.77,
    // realistic ~0.05. margin 2.0 >= 2*e_max keeps recall; exact f64 recheck follows.
    const float T = t5[4] + 2.0f;
    int cnt = 0, ov = 0;
    int* cq = cand + (size_t)(b * NTOK + q0 + q) * (CAND + 4);
    for (int s = 0; s < 4; ++s) {
      if (U.M.mv[q + s * 64][9] < T) ov = 1;          // slice may hide candidates
      for (int j = 0; j < 10; ++j) {
        const float v = U.M.mv[q + s * 64][j];
        if (v <= T && cnt < CAND) { cq[1 + cnt] = (int)U.M.mi[q + s * 64][j]; ++cnt; }
      }
    }
    cq[0] = ov ? -1 : cnt;
  }
}

// ---------------- kernel 3: exact f64 kNN distance on candidates ----------------
__global__ __launch_bounds__(256) void exact_knn_kernel(
    const float* __restrict__ x, const int* __restrict__ cand,
    double* __restrict__ dk2) {
  const int qg = blockIdx.x * 4 + (threadIdx.x >> 6);   // [0, BATCH*NTOK)
  const int l  = threadIdx.x & 63;
  const int b  = qg >> 12;
  const int q  = qg & (NTOK - 1);
  const float* xb = x + (size_t)b * NTOK * DIM;
  const int* cq = cand + (size_t)qg * (CAND + 4);
  const int cnt = cq[0];

  double xq[4];
#pragma unroll
  for (int i = 0; i < 4; ++i) xq[i] = (double)xb[(size_t)q * DIM + l + i * 64];

  double t5[5] = {1e300, 1e300, 1e300, 1e300, 1e300};
  const int n_iter = (cnt >= 0) ? cnt : NTOK;
  for (int c = 0; c < n_iter; ++c) {
    int m;
    if (cnt >= 0) m = cq[1 + c];
    else { m = c; if (m == q) continue; }
    double acc = 0.0;
#pragma unroll
    for (int i = 0; i < 4; ++i) {
      const double d = xq[i] - (double)xb[(size_t)m * DIM + l + i * 64];
      acc += d * d;
    }
#pragma unroll
    for (int off = 32; off > 0; off >>= 1) acc += __shfl_xor(acc, off, 64);
    if (acc < t5[4]) {
      t5[4] = acc;
#pragma unroll
      for (int k2 = 4; k2 > 0; --k2)
        if (t5[k2] < t5[k2 - 1]) { double tmp = t5[k2]; t5[k2] = t5[k2 - 1]; t5[k2 - 1] = tmp; }
    }
  }
  if (l == 0) dk2[qg] = t5[4];
}

// ---------------- kernel 4: gumbel + score (f64) ----------------
__global__ __launch_bounds__(256) void score_kernel(const double* __restrict__ dk2,
                                                    double* __restrict__ scores) {
  const int i = blockIdx.x * 256 + threadIdx.x;
  const uint32_t bits = threefry_bits32(0u, (uint32_t)i);
  const uint32_t fb = (bits >> 9) | 0x3F800000u;
  float uf = __uint_as_float(fb) - 1.0f;
  const float tiny = 1.17549435082228750797e-38f;
  uf += tiny;
  if (uf < tiny) uf = tiny;
  const double g = -log(-log((double)uf));
  const double w = sqrt(dk2[i] + 1e-12);
  scores[i] = log(w + 1e-12) + g;
}

// ---------------- kernel 5: per-batch bitonic full sort -> top-256 idx ----------
__global__ __launch_bounds__(256) void sort_topk_kernel(
    const double* __restrict__ scores, int* __restrict__ sel) {
  __shared__ unsigned long long ko[NTOK];              // 32 KB
  __shared__ int ki[NTOK];                             // 16 KB
  const int b = blockIdx.x;
  const int t = threadIdx.x;
  for (int i = t; i < NTOK; i += 256) {
    const double s = scores[(size_t)b * NTOK + i];
    unsigned long long u = (unsigned long long)__double_as_longlong(s);
    u = (u & 0x8000000000000000ull) ? ~u : (u | 0x8000000000000000ull);
    ko[i] = u; ki[i] = i;
  }
  __syncthreads();
  for (int k = 2; k <= NTOK; k <<= 1) {
    for (int j = k >> 1; j > 0; j >>= 1) {
      for (int base = 0; base < NTOK; base += 256) {
        const int i = base + t;
        const int p = i ^ j;
        if (p > i) {
          const bool up = (i & k) == 0;                // up-blocks sort descending
          unsigned long long a = ko[i], c = ko[p];
          int ia = ki[i], ic = ki[p];
          const bool p_beats = (c > a) || (c == a && ic < ia);
          const bool i_beats = (a > c) || (a == c && ia < ic);
          const bool sw = up ? p_beats : i_beats;
          if (sw) { ko[i] = c; ko[p] = a; ki[i] = ic; ki[p] = ia; }
        }
      }
      __syncthreads();
    }
  }
  if (t < SK) sel[b * SK + t] = ki[t];
}

// ---------------- kernel 6: gather sampled rows ----------------
__global__ __launch_bounds__(256) void gather_kernel(const float* __restrict__ x,
                                                     const int* __restrict__ sel,
                                                     float* __restrict__ out) {
  const int blk = blockIdx.x;                          // 8*256 blocks
  const int b = blk >> 8;
  const int r = blk & 255;
  const int t = threadIdx.x;
  const int src = sel[b * SK + r];
  out[((size_t)(b * SK + r)) * DIM + t] = x[((size_t)(b * NTOK + src)) * DIM + t];
  if (blk == 0 && t == 0) out[(size_t)BATCH * SK * DIM] = 0.0f;  // 2nd output: 0.0
}

extern "C" void kernel_launch(void* const* d_in, const int* in_sizes, int n_in,
                              void* d_out, int out_size, void* d_ws, size_t ws_size,
                              hipStream_t stream) {
  const float* x = (const float*)d_in[0];
  float* out = (float*)d_out;
  char* ws = (char*)d_ws;

  double* dk2     = (double*)(ws + 0);                 // 256 KB
  double* scores  = (double*)(ws + 262144);            // 256 KB
  float*  sqf     = (float*)(ws + 524288);             // 128 KB
  int*    sel     = (int*)(ws + 655360);               // 8 KB
  unsigned short* xh = (unsigned short*)(ws + 1048576);    // 16 MB (fp16)
  int*    cand    = (int*)(ws + 17825792);             // 5.8 MB  (total ~24 MB)

  tofp16_rowsq_kernel<<<BATCH * NTOK / 4, 256, 0, stream>>>(x, xh, sqf);
  gemm_knn_kernel<<<BATCH * (NTOK / BQ), 256, 0, stream>>>(xh, sqf, cand);
  exact_knn_kernel<<<BATCH * NTOK / 4, 256, 0, stream>>>(x, cand, dk2);
  score_kernel<<<BATCH * NTOK / 256, 256, 0, stream>>>(dk2, scores);
  sort_topk_kernel<<<BATCH, 256, 0, stream>>>(scores, sel);
  gather_kernel<<<BATCH * SK, 256, 0, stream>>>(x, sel, out);
}